// Round 4
// baseline (343.948 us; speedup 1.0000x reference)
//
#include <hip/hip_runtime.h>
#include <math.h>

#define N_NODES 20000
#define KNBR 32
#define DIM 128
#define EDIM 64
#define HEADS 8
#define OUTD 128
#define FFD 512
#define LN_EPS 1e-5f

typedef __attribute__((ext_vector_type(8))) short short8v;
typedef __attribute__((ext_vector_type(4))) float f32x4;

__device__ __forceinline__ unsigned short f2bf(float f) {
    unsigned u = __builtin_bit_cast(unsigned, f);
    u += 0x7fffu + ((u >> 16) & 1u);
    return (unsigned short)(u >> 16);
}
__device__ __forceinline__ float bfhi2f(unsigned u_hi16) {  // bf16 in high 16 bits
    return __builtin_bit_cast(float, u_hi16);
}

// ---------------------------------------------------------------------------
// K0: weight prep (bf16, B-fragment-friendly transposed layouts)
//   WkvT[c][k] = [Wk|Wv][128+k][c]        (256 x 64)
//   WoT [c][d] = Wo[d][c]                 (128 x 128)
//   W1T [f][d] = W1[d][f]                 (512 x 128)
//   W2T [c][f] = W2[f][c]                 (128 x 512)
// ---------------------------------------------------------------------------
__global__ __launch_bounds__(256) void k0_prep(
    const float* __restrict__ Wk, const float* __restrict__ Wv,
    const float* __restrict__ Wo, const float* __restrict__ W1,
    const float* __restrict__ W2,
    unsigned short* __restrict__ WkvT, unsigned short* __restrict__ WoT,
    unsigned short* __restrict__ W1T, unsigned short* __restrict__ W2T)
{
    const int idx = blockIdx.x * 256 + threadIdx.x;   // 163840 total
    if (idx < 16384) {
        const int c = idx >> 6, k = idx & 63;
        WkvT[idx] = f2bf((c < 128) ? Wk[(size_t)(128 + k) * 128 + c]
                                   : Wv[(size_t)(128 + k) * 128 + (c - 128)]);
    } else if (idx < 32768) {
        const int j = idx - 16384, c = j >> 7, d = j & 127;
        WoT[j] = f2bf(Wo[(size_t)d * 128 + c]);
    } else if (idx < 98304) {
        const int j = idx - 32768, f = j >> 7, d = j & 127;
        W1T[j] = f2bf(W1[(size_t)d * 512 + f]);
    } else {
        const int j = idx - 98304, c = j >> 9, f = j & 511;
        W2T[j] = f2bf(W2[(size_t)f * 128 + c]);
    }
}

// ---------------------------------------------------------------------------
// K1: x = LN(node_rep)*mask -> xout ; q = x@Wq+bq -> qout ;
//     P = x@[Wk_x|Wv_x] + [bk|bv] -> Pp (bf16, ROW-MAJOR [n][256])
// ---------------------------------------------------------------------------
__global__ __launch_bounds__(256) void k1_ln_q_p(
    const float* __restrict__ node_rep, const float* __restrict__ mask,
    const float* __restrict__ ln1_s, const float* __restrict__ ln1_b,
    const float* __restrict__ Wq, const float* __restrict__ bq,
    const float* __restrict__ Wk, const float* __restrict__ bk,
    const float* __restrict__ Wv, const float* __restrict__ bv,
    float* __restrict__ xout, float* __restrict__ qout,
    unsigned short* __restrict__ Pp)
{
    __shared__ float xs[8][DIM];
    const int t = threadIdx.x;
    const int nb = blockIdx.x * 8;
    const int g = t >> 5;
    const int lane = t & 31;
    const int node = nb + g;

    float4 v = reinterpret_cast<const float4*>(node_rep + (size_t)node * DIM)[lane];
    float s1 = v.x + v.y + v.z + v.w;
    float s2 = v.x * v.x + v.y * v.y + v.z * v.z + v.w * v.w;
    #pragma unroll
    for (int off = 16; off; off >>= 1) {
        s1 += __shfl_xor(s1, off, 32);
        s2 += __shfl_xor(s2, off, 32);
    }
    const float mean = s1 * (1.0f / DIM);
    const float var  = s2 * (1.0f / DIM) - mean * mean;
    const float rs   = rsqrtf(var + LN_EPS);
    const float mk   = mask[node];

    float4 sc = reinterpret_cast<const float4*>(ln1_s)[lane];
    float4 of = reinterpret_cast<const float4*>(ln1_b)[lane];
    float4 xo;
    xo.x = ((v.x - mean) * rs * sc.x + of.x) * mk;
    xo.y = ((v.y - mean) * rs * sc.y + of.y) * mk;
    xo.z = ((v.z - mean) * rs * sc.z + of.z) * mk;
    xo.w = ((v.w - mean) * rs * sc.w + of.w) * mk;
    reinterpret_cast<float4*>(xout + (size_t)node * DIM)[lane] = xo;
    const int c0 = lane * 4;
    xs[g][c0 + 0] = xo.x; xs[g][c0 + 1] = xo.y;
    xs[g][c0 + 2] = xo.z; xs[g][c0 + 3] = xo.w;
    __syncthreads();

    const int col = t & 127;
    const int n0  = t >> 7;
    const int c = t;
    const float* wq = Wq + col;
    const float* wp = (c < 128) ? (Wk + c) : (Wv + (c - 128));

    float accq[4] = {0.f, 0.f, 0.f, 0.f};
    float accp[8] = {0.f, 0.f, 0.f, 0.f, 0.f, 0.f, 0.f, 0.f};
    for (int d = 0; d < DIM; ++d) {
        const float wqd = wq[(size_t)d * 128];
        const float wpd = wp[(size_t)d * 128];
        #pragma unroll
        for (int i = 0; i < 4; ++i) accq[i] += xs[n0 + 2 * i][d] * wqd;
        #pragma unroll
        for (int i = 0; i < 8; ++i) accp[i] += xs[i][d] * wpd;
    }
    const float bqv = bq[col];
    #pragma unroll
    for (int i = 0; i < 4; ++i)
        qout[(size_t)(nb + n0 + 2 * i) * DIM + col] = accq[i] + bqv;

    const float bpv = (c < 128) ? bk[c] : bv[c - 128];
    #pragma unroll
    for (int i = 0; i < 8; ++i)
        Pp[(size_t)(nb + i) * 256 + c] = f2bf(accp[i] + bpv);
}

// ---------------------------------------------------------------------------
// K2: per-node attention via SWAPPED MFMA (A = WkvT rows, B = edge rows).
//   C-layout: acc[ct][rt][i] = kkvv^T[c = 16ct + lg*4 + i][nbr = 16rt + l15]
//   -> logits d-reduction = 4 local FMA + 2 shfl; attn lane-local per nbr;
//      PV = 8 FMA + 4-stage l15 reduce. 1 wave = 1 node, no LDS.
// ---------------------------------------------------------------------------
__global__ __launch_bounds__(256, 2) void k2_attn(
    const float* __restrict__ qg, const float* __restrict__ edge_feat,
    const unsigned short* __restrict__ Pp,
    const unsigned short* __restrict__ WkvT,
    const int* __restrict__ senders,
    float* __restrict__ og)
{
    const int t = threadIdx.x;
    const int w = t >> 6, l = t & 63;
    const int n = blockIdx.x * 4 + w;
    const int l15 = l & 15, lg = l >> 4;

    // per-lane neighbor indices for the two column halves
    const int sr0 = senders[n * KNBR + l15];
    const int sr1 = senders[n * KNBR + 16 + l15];

    // B fragments: edge rows (lane l15 = neighbor), k = d at s*32 + lg*8
    short8v be[2][2];
    #pragma unroll
    for (int rt = 0; rt < 2; ++rt) {
        #pragma unroll
        for (int s = 0; s < 2; ++s) {
            const float* ep = edge_feat
                + ((size_t)n * KNBR + 16 * rt + l15) * EDIM + s * 32 + lg * 8;
            const float4 e0 = *reinterpret_cast<const float4*>(ep);
            const float4 e1 = *reinterpret_cast<const float4*>(ep + 4);
            short8v b;
            b[0] = (short)f2bf(e0.x); b[1] = (short)f2bf(e0.y);
            b[2] = (short)f2bf(e0.z); b[3] = (short)f2bf(e0.w);
            b[4] = (short)f2bf(e1.x); b[5] = (short)f2bf(e1.y);
            b[6] = (short)f2bf(e1.z); b[7] = (short)f2bf(e1.w);
            be[rt][s] = b;
        }
    }

    f32x4 acc[16][2];
    #pragma unroll
    for (int ct = 0; ct < 16; ++ct) {
        acc[ct][0] = (f32x4){0.f, 0.f, 0.f, 0.f};
        acc[ct][1] = (f32x4){0.f, 0.f, 0.f, 0.f};
    }

    // MFMA: D[c][nbr] — A = WkvT row c (lane l15), B = edge row nbr (lane l15)
    #pragma unroll
    for (int ct = 0; ct < 16; ++ct) {
        #pragma unroll
        for (int s = 0; s < 2; ++s) {
            const short8v a = *reinterpret_cast<const short8v*>(
                WkvT + (size_t)(16 * ct + l15) * EDIM + s * 32 + lg * 8);
            acc[ct][0] = __builtin_amdgcn_mfma_f32_16x16x32_bf16(
                a, be[0][s], acc[ct][0], 0, 0, 0);
            acc[ct][1] = __builtin_amdgcn_mfma_f32_16x16x32_bf16(
                a, be[1][s], acc[ct][1], 0, 0, 0);
        }
    }

    // P gather & add: acc[ct][rt][i] += P[snd[16rt+l15]][16ct + lg*4 + i]
    const unsigned short* p0 = Pp + (size_t)sr0 * 256 + lg * 4;
    const unsigned short* p1 = Pp + (size_t)sr1 * 256 + lg * 4;
    #pragma unroll
    for (int ct = 0; ct < 16; ++ct) {
        const uint2 u0 = *reinterpret_cast<const uint2*>(p0 + 16 * ct);
        const uint2 u1 = *reinterpret_cast<const uint2*>(p1 + 16 * ct);
        acc[ct][0][0] += bfhi2f(u0.x << 16);
        acc[ct][0][1] += bfhi2f(u0.x & 0xffff0000u);
        acc[ct][0][2] += bfhi2f(u0.y << 16);
        acc[ct][0][3] += bfhi2f(u0.y & 0xffff0000u);
        acc[ct][1][0] += bfhi2f(u1.x << 16);
        acc[ct][1][1] += bfhi2f(u1.x & 0xffff0000u);
        acc[ct][1][2] += bfhi2f(u1.y << 16);
        acc[ct][1][3] += bfhi2f(u1.y & 0xffff0000u);
    }

    // epilogue per head: logits -> softmax -> PV (all short chains)
    #pragma unroll
    for (int h = 0; h < 8; ++h) {
        const float4 q4 = *reinterpret_cast<const float4*>(
            qg + (size_t)n * DIM + h * 16 + lg * 4);
        float tm0 = q4.x * acc[h][0][0] + q4.y * acc[h][0][1]
                  + q4.z * acc[h][0][2] + q4.w * acc[h][0][3];
        float tm1 = q4.x * acc[h][1][0] + q4.y * acc[h][1][1]
                  + q4.z * acc[h][1][2] + q4.w * acc[h][1][3];
        // sum over d-blocks (lg groups)
        tm0 += __shfl_xor(tm0, 16, 64); tm0 += __shfl_xor(tm0, 32, 64);
        tm1 += __shfl_xor(tm1, 16, 64); tm1 += __shfl_xor(tm1, 32, 64);
        // max over 32 neighbors
        float m = fmaxf(tm0, tm1);
        #pragma unroll
        for (int off = 1; off <= 8; off <<= 1)
            m = fmaxf(m, __shfl_xor(m, off, 64));
        const float e0 = __expf((tm0 - m) * 0.25f);
        const float e1 = __expf((tm1 - m) * 0.25f);
        float s = e0 + e1;
        #pragma unroll
        for (int off = 1; off <= 8; off <<= 1)
            s += __shfl_xor(s, off, 64);
        const float inv = 1.0f / s;
        // PV: per-lane partial over its 2 neighbors, then reduce over l15
        float pv[4];
        #pragma unroll
        for (int i = 0; i < 4; ++i)
            pv[i] = e0 * acc[8 + h][0][i] + e1 * acc[8 + h][1][i];
        #pragma unroll
        for (int off = 1; off <= 8; off <<= 1) {
            #pragma unroll
            for (int i = 0; i < 4; ++i)
                pv[i] += __shfl_xor(pv[i], off, 64);
        }
        if (l15 == h) {
            float4 o;
            o.x = pv[0] * inv; o.y = pv[1] * inv;
            o.z = pv[2] * inv; o.w = pv[3] * inv;
            *reinterpret_cast<float4*>(og + (size_t)n * DIM + h * 16 + lg * 4) = o;
        }
    }
}

// ---------------------------------------------------------------------------
// K3 (MFMA): res=o@Wo+bo; *mask; LN2 (in C-frag regs); h->LDS(bf16,swizzled);
//   chunked FF: t=relu(h@W1+b1) chunk->LDS; acc3 += t@W2 ; +b2,*mask,+x -> out
// ---------------------------------------------------------------------------
__device__ __forceinline__ void lds_wr16(unsigned short* base, int row, int col,
                                         unsigned short v) {
    const int byte = row * 256 + (((col * 2) ^ ((row & 7) << 4)));
    *reinterpret_cast<unsigned short*>(reinterpret_cast<char*>(base) + byte) = v;
}
__device__ __forceinline__ short8v lds_rd128(const unsigned short* base, int row,
                                             int colbyte) {
    const int byte = row * 256 + ((colbyte) ^ ((row & 7) << 4));
    return *reinterpret_cast<const short8v*>(
        reinterpret_cast<const char*>(base) + byte);
}

__global__ __launch_bounds__(256) void k3_ffn(
    const float* __restrict__ og, const float* __restrict__ xg,
    const float* __restrict__ mask,
    const unsigned short* __restrict__ WoT, const float* __restrict__ bo,
    const float* __restrict__ ln2_s, const float* __restrict__ ln2_b,
    const unsigned short* __restrict__ W1T, const float* __restrict__ b1,
    const unsigned short* __restrict__ W2T, const float* __restrict__ b2,
    float* __restrict__ outp)
{
    __shared__ unsigned short hls[64 * 128];
    __shared__ unsigned short tls[64 * 128];

    const int t = threadIdx.x;
    const int w = t >> 6, l = t & 63;
    const int l15 = l & 15, lg = l >> 4;
    const int nb = blockIdx.x * 64;
    const int arow = w * 16 + l15;
    const int anode = nb + arow;
    const int r0 = lg * 4;

    float mk[4];
    #pragma unroll
    for (int i = 0; i < 4; ++i) {
        const int node = nb + w * 16 + r0 + i;
        mk[i] = (node < N_NODES) ? mask[node] : 0.f;
    }

    f32x4 acc1[8];
    #pragma unroll
    for (int ct = 0; ct < 8; ++ct) acc1[ct] = (f32x4){0.f, 0.f, 0.f, 0.f};
    #pragma unroll
    for (int kc = 0; kc < 4; ++kc) {
        short8v afr = {0, 0, 0, 0, 0, 0, 0, 0};
        if (anode < N_NODES) {
            const float* op = og + (size_t)anode * DIM + kc * 32 + lg * 8;
            const float4 e0 = *reinterpret_cast<const float4*>(op);
            const float4 e1 = *reinterpret_cast<const float4*>(op + 4);
            afr[0] = (short)f2bf(e0.x); afr[1] = (short)f2bf(e0.y);
            afr[2] = (short)f2bf(e0.z); afr[3] = (short)f2bf(e0.w);
            afr[4] = (short)f2bf(e1.x); afr[5] = (short)f2bf(e1.y);
            afr[6] = (short)f2bf(e1.z); afr[7] = (short)f2bf(e1.w);
        }
        #pragma unroll
        for (int ct = 0; ct < 8; ++ct) {
            const short8v b = *reinterpret_cast<const short8v*>(
                WoT + (size_t)(ct * 16 + l15) * DIM + kc * 32 + lg * 8);
            acc1[ct] = __builtin_amdgcn_mfma_f32_16x16x32_bf16(afr, b, acc1[ct], 0, 0, 0);
        }
    }

    float s1[4] = {0.f, 0.f, 0.f, 0.f}, s2[4] = {0.f, 0.f, 0.f, 0.f};
    #pragma unroll
    for (int ct = 0; ct < 8; ++ct) {
        const float bov = bo[ct * 16 + l15];
        #pragma unroll
        for (int i = 0; i < 4; ++i) {
            const float v2 = (acc1[ct][i] + bov) * mk[i];
            acc1[ct][i] = v2;
            s1[i] += v2; s2[i] += v2 * v2;
        }
    }
    #pragma unroll
    for (int off = 1; off <= 8; off <<= 1) {
        #pragma unroll
        for (int i = 0; i < 4; ++i) {
            s1[i] += __shfl_xor(s1[i], off, 64);
            s2[i] += __shfl_xor(s2[i], off, 64);
        }
    }
    float mean[4], rsv[4];
    #pragma unroll
    for (int i = 0; i < 4; ++i) {
        mean[i] = s1[i] * (1.0f / OUTD);
        const float var = s2[i] * (1.0f / OUTD) - mean[i] * mean[i];
        rsv[i] = rsqrtf(var + LN_EPS);
    }
    #pragma unroll
    for (int ct = 0; ct < 8; ++ct) {
        const int col = ct * 16 + l15;
        const float sc = ln2_s[col], ofs = ln2_b[col];
        #pragma unroll
        for (int i = 0; i < 4; ++i) {
            const float h = (acc1[ct][i] - mean[i]) * rsv[i] * sc + ofs;
            lds_wr16(hls, w * 16 + r0 + i, col, f2bf(h));
        }
    }
    __syncthreads();

    short8v hfr[4];
    #pragma unroll
    for (int kc = 0; kc < 4; ++kc)
        hfr[kc] = lds_rd128(hls, arow, kc * 64 + lg * 16);

    f32x4 acc3[8];
    #pragma unroll
    for (int ct = 0; ct < 8; ++ct) acc3[ct] = (f32x4){0.f, 0.f, 0.f, 0.f};

    for (int chunk = 0; chunk < 4; ++chunk) {
        f32x4 acc2[8];
        #pragma unroll
        for (int ct = 0; ct < 8; ++ct) acc2[ct] = (f32x4){0.f, 0.f, 0.f, 0.f};
        #pragma unroll
        for (int kc = 0; kc < 4; ++kc) {
            #pragma unroll
            for (int ct = 0; ct < 8; ++ct) {
                const short8v b = *reinterpret_cast<const short8v*>(
                    W1T + (size_t)(chunk * 128 + ct * 16 + l15) * DIM + kc * 32 + lg * 8);
                acc2[ct] = __builtin_amdgcn_mfma_f32_16x16x32_bf16(hfr[kc], b, acc2[ct], 0, 0, 0);
            }
        }
        #pragma unroll
        for (int ct = 0; ct < 8; ++ct) {
            const float bv = b1[chunk * 128 + ct * 16 + l15];
            #pragma unroll
            for (int i = 0; i < 4; ++i) {
                const float tv = fmaxf(acc2[ct][i] + bv, 0.f);
                lds_wr16(tls, w * 16 + r0 + i, ct * 16 + l15, f2bf(tv));
            }
        }
        __syncthreads();
        #pragma unroll
        for (int kc = 0; kc < 4; ++kc) {
            const short8v tfr = lds_rd128(tls, arow, kc * 64 + lg * 16);
            #pragma unroll
            for (int ct = 0; ct < 8; ++ct) {
                const short8v b = *reinterpret_cast<const short8v*>(
                    W2T + (size_t)(ct * 16 + l15) * FFD + chunk * 128 + kc * 32 + lg * 8);
                acc3[ct] = __builtin_amdgcn_mfma_f32_16x16x32_bf16(tfr, b, acc3[ct], 0, 0, 0);
            }
        }
        __syncthreads();
    }

    #pragma unroll
    for (int ct = 0; ct < 8; ++ct) {
        const int col = ct * 16 + l15;
        const float b2v = b2[col];
        #pragma unroll
        for (int i = 0; i < 4; ++i) {
            const int node = nb + w * 16 + r0 + i;
            if (node < N_NODES) {
                const float f = (acc3[ct][i] + b2v) * mk[i];
                outp[(size_t)node * DIM + col] = xg[(size_t)node * DIM + col] + f;
            }
        }
    }
}

// ---------------------------------------------------------------------------
extern "C" void kernel_launch(void* const* d_in, const int* in_sizes, int n_in,
                              void* d_out, int out_size, void* d_ws, size_t ws_size,
                              hipStream_t stream)
{
    const float* node_rep = (const float*)d_in[0];
    const float* mask     = (const float*)d_in[1];
    const float* edge_feat= (const float*)d_in[2];
    const float* Wq = (const float*)d_in[3];
    const float* bq = (const float*)d_in[4];
    const float* Wk = (const float*)d_in[5];
    const float* bk = (const float*)d_in[6];
    const float* Wv = (const float*)d_in[7];
    const float* bv = (const float*)d_in[8];
    const float* Wo = (const float*)d_in[9];
    const float* bo = (const float*)d_in[10];
    const float* ln1_s = (const float*)d_in[11];
    const float* ln1_b = (const float*)d_in[12];
    const float* ln2_s = (const float*)d_in[13];
    const float* ln2_b = (const float*)d_in[14];
    const float* W1 = (const float*)d_in[15];
    const float* b1 = (const float*)d_in[16];
    const float* W2 = (const float*)d_in[17];
    const float* b2 = (const float*)d_in[18];
    const int* senders = (const int*)d_in[19];

    float* out = (float*)d_out;
    float* xg = (float*)d_ws;                           // [N,128] f32
    float* qg = xg + (size_t)N_NODES * DIM;             // [N,128] f32
    float* og = qg + (size_t)N_NODES * DIM;             // [N,128] f32
    unsigned short* Pp   = (unsigned short*)(og + (size_t)N_NODES * DIM);  // [N,256] bf16
    unsigned short* WkvT = Pp + (size_t)N_NODES * 256;  // [256,64]
    unsigned short* WoT  = WkvT + 256 * 64;             // [128,128]
    unsigned short* W1T  = WoT + 128 * 128;             // [512,128]
    unsigned short* W2T  = W1T + 512 * 128;             // [128,512]

    hipLaunchKernelGGL(k0_prep, dim3(640), dim3(256), 0, stream,
                       Wk, Wv, Wo, W1, W2, WkvT, WoT, W1T, W2T);
    hipLaunchKernelGGL(k1_ln_q_p, dim3(N_NODES / 8), dim3(256), 0, stream,
                       node_rep, mask, ln1_s, ln1_b, Wq, bq, Wk, bk, Wv, bv,
                       xg, qg, Pp);
    hipLaunchKernelGGL(k2_attn, dim3(N_NODES / 4), dim3(256), 0, stream,
                       qg, edge_feat, Pp, WkvT, senders, og);
    hipLaunchKernelGGL(k3_ffn, dim3((N_NODES + 63) / 64), dim3(256), 0, stream,
                       og, xg, mask, WoT, bo, ln2_s, ln2_b, W1T, b1, W2T, b2, out);
}

// Round 5
// 292.759 us; speedup vs baseline: 1.1748x; 1.1748x over previous
//
#include <hip/hip_runtime.h>
#include <math.h>

#define N_NODES 20000
#define KNBR 32
#define DIM 128
#define EDIM 64
#define HEADS 8
#define OUTD 128
#define FFD 512
#define LN_EPS 1e-5f

typedef __attribute__((ext_vector_type(8))) short short8v;
typedef __attribute__((ext_vector_type(4))) float f32x4;

__device__ __forceinline__ unsigned short f2bf(float f) {
    unsigned u = __builtin_bit_cast(unsigned, f);
    u += 0x7fffu + ((u >> 16) & 1u);
    return (unsigned short)(u >> 16);
}
__device__ __forceinline__ float bfhi2f(unsigned u_hi16) {  // bf16 in high 16 bits
    return __builtin_bit_cast(float, u_hi16);
}

// DPP 16-lane all-lanes sum: xor1(quad_perm[1,0,3,2]=0xB1), xor2(quad_perm
// [2,3,0,1]=0x4E), half_mirror(0x141), mirror(0x140). VALU-only, no DS pipe.
template <int CTRL>
__device__ __forceinline__ float dpp_addf(float x) {
    const int s = __builtin_bit_cast(int, x);
    const int p = __builtin_amdgcn_update_dpp(s, s, CTRL, 0xF, 0xF, true);
    return x + __builtin_bit_cast(float, p);
}
__device__ __forceinline__ float red16(float x) {
    x = dpp_addf<0xB1>(x);
    x = dpp_addf<0x4E>(x);
    x = dpp_addf<0x141>(x);
    x = dpp_addf<0x140>(x);
    return x;
}

// ---------------------------------------------------------------------------
// K0: weight prep (bf16, B-fragment-friendly transposed layouts)
// ---------------------------------------------------------------------------
__global__ __launch_bounds__(256) void k0_prep(
    const float* __restrict__ Wk, const float* __restrict__ Wv,
    const float* __restrict__ Wo, const float* __restrict__ W1,
    const float* __restrict__ W2,
    unsigned short* __restrict__ WkvT, unsigned short* __restrict__ WoT,
    unsigned short* __restrict__ W1T, unsigned short* __restrict__ W2T)
{
    const int idx = blockIdx.x * 256 + threadIdx.x;   // 163840 total
    if (idx < 16384) {
        const int c = idx >> 6, k = idx & 63;
        WkvT[idx] = f2bf((c < 128) ? Wk[(size_t)(128 + k) * 128 + c]
                                   : Wv[(size_t)(128 + k) * 128 + (c - 128)]);
    } else if (idx < 32768) {
        const int j = idx - 16384, c = j >> 7, d = j & 127;
        WoT[j] = f2bf(Wo[(size_t)d * 128 + c]);
    } else if (idx < 98304) {
        const int j = idx - 32768, f = j >> 7, d = j & 127;
        W1T[j] = f2bf(W1[(size_t)d * 512 + f]);
    } else {
        const int j = idx - 98304, c = j >> 9, f = j & 511;
        W2T[j] = f2bf(W2[(size_t)f * 128 + c]);
    }
}

// ---------------------------------------------------------------------------
// K1: x = LN(node_rep)*mask -> xout ; q = x@Wq+bq -> qout ;
//     P = x@[Wk_x|Wv_x] + [bk|bv] -> Pp (bf16, MFMA-col-packed layout)
// Pp layout: Pp[n*256 + g*64 + d*4 + j] = P[n][(4g+j)*16 + d]
// ---------------------------------------------------------------------------
__global__ __launch_bounds__(256) void k1_ln_q_p(
    const float* __restrict__ node_rep, const float* __restrict__ mask,
    const float* __restrict__ ln1_s, const float* __restrict__ ln1_b,
    const float* __restrict__ Wq, const float* __restrict__ bq,
    const float* __restrict__ Wk, const float* __restrict__ bk,
    const float* __restrict__ Wv, const float* __restrict__ bv,
    float* __restrict__ xout, float* __restrict__ qout,
    unsigned short* __restrict__ Pp)
{
    __shared__ float xs[8][DIM];
    const int t = threadIdx.x;
    const int nb = blockIdx.x * 8;
    const int g = t >> 5;
    const int lane = t & 31;
    const int node = nb + g;

    float4 v = reinterpret_cast<const float4*>(node_rep + (size_t)node * DIM)[lane];
    float s1 = v.x + v.y + v.z + v.w;
    float s2 = v.x * v.x + v.y * v.y + v.z * v.z + v.w * v.w;
    #pragma unroll
    for (int off = 16; off; off >>= 1) {
        s1 += __shfl_xor(s1, off, 32);
        s2 += __shfl_xor(s2, off, 32);
    }
    const float mean = s1 * (1.0f / DIM);
    const float var  = s2 * (1.0f / DIM) - mean * mean;
    const float rs   = rsqrtf(var + LN_EPS);
    const float mk   = mask[node];

    float4 sc = reinterpret_cast<const float4*>(ln1_s)[lane];
    float4 of = reinterpret_cast<const float4*>(ln1_b)[lane];
    float4 xo;
    xo.x = ((v.x - mean) * rs * sc.x + of.x) * mk;
    xo.y = ((v.y - mean) * rs * sc.y + of.y) * mk;
    xo.z = ((v.z - mean) * rs * sc.z + of.z) * mk;
    xo.w = ((v.w - mean) * rs * sc.w + of.w) * mk;
    reinterpret_cast<float4*>(xout + (size_t)node * DIM)[lane] = xo;
    const int c0 = lane * 4;
    xs[g][c0 + 0] = xo.x; xs[g][c0 + 1] = xo.y;
    xs[g][c0 + 2] = xo.z; xs[g][c0 + 3] = xo.w;
    __syncthreads();

    const int col = t & 127;
    const int n0  = t >> 7;
    const int c = t;
    const float* wq = Wq + col;
    const float* wp = (c < 128) ? (Wk + c) : (Wv + (c - 128));

    float accq[4] = {0.f, 0.f, 0.f, 0.f};
    float accp[8] = {0.f, 0.f, 0.f, 0.f, 0.f, 0.f, 0.f, 0.f};
    for (int d = 0; d < DIM; ++d) {
        const float wqd = wq[(size_t)d * 128];
        const float wpd = wp[(size_t)d * 128];
        #pragma unroll
        for (int i = 0; i < 4; ++i) accq[i] += xs[n0 + 2 * i][d] * wqd;
        #pragma unroll
        for (int i = 0; i < 8; ++i) accp[i] += xs[i][d] * wpd;
    }
    const float bqv = bq[col];
    #pragma unroll
    for (int i = 0; i < 4; ++i)
        qout[(size_t)(nb + n0 + 2 * i) * DIM + col] = accq[i] + bqv;

    const float bpv = (c < 128) ? bk[c] : bv[c - 128];
    const int pos = (c >> 6) * 64 + (c & 15) * 4 + ((c >> 4) & 3);
    #pragma unroll
    for (int i = 0; i < 8; ++i)
        Pp[(size_t)(nb + i) * 256 + pos] = f2bf(accp[i] + bpv);
}

// ---------------------------------------------------------------------------
// K2: per-node attention via MFMA (round-3 memory structure: wave-uniform
// P gather), epilogue butterflies replaced by DPP (VALU) reductions.
// 1 wave = 1 node, 4 nodes/block, no LDS.
// ---------------------------------------------------------------------------
__global__ __launch_bounds__(256, 2) void k2_attn(
    const float* __restrict__ qg, const float* __restrict__ edge_feat,
    const unsigned short* __restrict__ Pp,
    const unsigned short* __restrict__ WkvT,
    const int* __restrict__ senders,
    float* __restrict__ og)
{
    const int t = threadIdx.x;
    const int w = t >> 6, l = t & 63;
    const int n = blockIdx.x * 4 + w;
    const int l15 = l & 15, lg = l >> 4;

    const int snd0 = senders[n * KNBR + (l & 31)];

    // per-head q values for this lane's column: q[h*16 + l15]
    float qreg[8];
    #pragma unroll
    for (int h = 0; h < 8; ++h)
        qreg[h] = qg[(size_t)n * DIM + h * 16 + l15];

    f32x4 acc[2][16];
    #pragma unroll
    for (int r = 0; r < 2; ++r)
        #pragma unroll
        for (int cc = 0; cc < 16; ++cc)
            acc[r][cc] = (f32x4){0.f, 0.f, 0.f, 0.f};

    // A fragments: edge rows, f32 -> bf16
    short8v afr[2][2];
    #pragma unroll
    for (int r = 0; r < 2; ++r) {
        #pragma unroll
        for (int s = 0; s < 2; ++s) {
            const float* ep = edge_feat
                + ((size_t)n * KNBR + 16 * r + l15) * EDIM + s * 32 + lg * 8;
            const float4 e0 = *reinterpret_cast<const float4*>(ep);
            const float4 e1 = *reinterpret_cast<const float4*>(ep + 4);
            short8v a;
            a[0] = (short)f2bf(e0.x); a[1] = (short)f2bf(e0.y);
            a[2] = (short)f2bf(e0.z); a[3] = (short)f2bf(e0.w);
            a[4] = (short)f2bf(e1.x); a[5] = (short)f2bf(e1.y);
            a[6] = (short)f2bf(e1.z); a[7] = (short)f2bf(e1.w);
            afr[r][s] = a;
        }
    }

    // MFMA: acc[r][c] += A[r][s] * B[c][s]
    #pragma unroll
    for (int cc = 0; cc < 16; ++cc) {
        #pragma unroll
        for (int s = 0; s < 2; ++s) {
            const short8v b = *reinterpret_cast<const short8v*>(
                WkvT + (size_t)(16 * cc + l15) * EDIM + s * 32 + lg * 8);
            acc[0][cc] = __builtin_amdgcn_mfma_f32_16x16x32_bf16(
                afr[0][s], b, acc[0][cc], 0, 0, 0);
            acc[1][cc] = __builtin_amdgcn_mfma_f32_16x16x32_bf16(
                afr[1][s], b, acc[1][cc], 0, 0, 0);
        }
    }

    // P gather & add (wave-uniform row broadcast, coalesced packed reads):
    // lane element (r, i) lives at row = 16r + lg*4 + i, col 16c+l15
    #pragma unroll
    for (int r = 0; r < 2; ++r) {
        #pragma unroll
        for (int i = 0; i < 4; ++i) {
            const int row = 16 * r + lg * 4 + i;
            const int sr = __shfl(snd0, row, 64);
            const unsigned short* pp = Pp + (size_t)sr * 256 + l15 * 4;
            #pragma unroll
            for (int g = 0; g < 4; ++g) {
                const uint2 u = *reinterpret_cast<const uint2*>(pp + g * 64);
                acc[r][g * 4 + 0][i] += bfhi2f(u.x << 16);
                acc[r][g * 4 + 1][i] += bfhi2f(u.x & 0xffff0000u);
                acc[r][g * 4 + 2][i] += bfhi2f(u.y << 16);
                acc[r][g * 4 + 3][i] += bfhi2f(u.y & 0xffff0000u);
            }
        }
    }

    // epilogue per head: logits -> softmax -> PV. DPP reductions (no DS).
    #pragma unroll
    for (int h = 0; h < 8; ++h) {
        const float qv = qreg[h];
        float tm[8];
        #pragma unroll
        for (int r = 0; r < 2; ++r)
            #pragma unroll
            for (int i = 0; i < 4; ++i)
                tm[r * 4 + i] = acc[r][h][i] * qv;
        // sum over l15 (feature dim of head) -> all lanes, VALU-only
        #pragma unroll
        for (int k = 0; k < 8; ++k) tm[k] = red16(tm[k]);
        // max over 32 neighbors: 8 local + cross-lg
        float m = tm[0];
        #pragma unroll
        for (int k = 1; k < 8; ++k) m = fmaxf(m, tm[k]);
        m = fmaxf(m, __shfl_xor(m, 16, 64));
        m = fmaxf(m, __shfl_xor(m, 32, 64));
        float s = 0.f, at[8];
        #pragma unroll
        for (int k = 0; k < 8; ++k) {
            at[k] = __expf((tm[k] - m) * 0.25f);
            s += at[k];
        }
        s += __shfl_xor(s, 16, 64);
        s += __shfl_xor(s, 32, 64);
        const float inv = 1.0f / s;
        float ov = 0.f;
        #pragma unroll
        for (int r = 0; r < 2; ++r)
            #pragma unroll
            for (int i = 0; i < 4; ++i)
                ov += at[r * 4 + i] * acc[r][8 + h][i];
        ov += __shfl_xor(ov, 16, 64);
        ov += __shfl_xor(ov, 32, 64);
        ov *= inv;
        if (lg == 0)
            og[(size_t)n * DIM + h * 16 + l15] = ov;
    }
}

// ---------------------------------------------------------------------------
// K3 (MFMA): res=o@Wo+bo; *mask; LN2 (in C-frag regs); h->LDS(bf16,swizzled);
//   chunked FF: t=relu(h@W1+b1) chunk->LDS; acc3 += t@W2 ; +b2,*mask,+x -> out
// ---------------------------------------------------------------------------
__device__ __forceinline__ void lds_wr16(unsigned short* base, int row, int col,
                                         unsigned short v) {
    const int byte = row * 256 + (((col * 2) ^ ((row & 7) << 4)));
    *reinterpret_cast<unsigned short*>(reinterpret_cast<char*>(base) + byte) = v;
}
__device__ __forceinline__ short8v lds_rd128(const unsigned short* base, int row,
                                             int colbyte) {
    const int byte = row * 256 + ((colbyte) ^ ((row & 7) << 4));
    return *reinterpret_cast<const short8v*>(
        reinterpret_cast<const char*>(base) + byte);
}

__global__ __launch_bounds__(256) void k3_ffn(
    const float* __restrict__ og, const float* __restrict__ xg,
    const float* __restrict__ mask,
    const unsigned short* __restrict__ WoT, const float* __restrict__ bo,
    const float* __restrict__ ln2_s, const float* __restrict__ ln2_b,
    const unsigned short* __restrict__ W1T, const float* __restrict__ b1,
    const unsigned short* __restrict__ W2T, const float* __restrict__ b2,
    float* __restrict__ outp)
{
    __shared__ unsigned short hls[64 * 128];
    __shared__ unsigned short tls[64 * 128];

    const int t = threadIdx.x;
    const int w = t >> 6, l = t & 63;
    const int l15 = l & 15, lg = l >> 4;
    const int nb = blockIdx.x * 64;
    const int arow = w * 16 + l15;
    const int anode = nb + arow;
    const int r0 = lg * 4;

    float mk[4];
    #pragma unroll
    for (int i = 0; i < 4; ++i) {
        const int node = nb + w * 16 + r0 + i;
        mk[i] = (node < N_NODES) ? mask[node] : 0.f;
    }

    f32x4 acc1[8];
    #pragma unroll
    for (int ct = 0; ct < 8; ++ct) acc1[ct] = (f32x4){0.f, 0.f, 0.f, 0.f};
    #pragma unroll
    for (int kc = 0; kc < 4; ++kc) {
        short8v afr = {0, 0, 0, 0, 0, 0, 0, 0};
        if (anode < N_NODES) {
            const float* op = og + (size_t)anode * DIM + kc * 32 + lg * 8;
            const float4 e0 = *reinterpret_cast<const float4*>(op);
            const float4 e1 = *reinterpret_cast<const float4*>(op + 4);
            afr[0] = (short)f2bf(e0.x); afr[1] = (short)f2bf(e0.y);
            afr[2] = (short)f2bf(e0.z); afr[3] = (short)f2bf(e0.w);
            afr[4] = (short)f2bf(e1.x); afr[5] = (short)f2bf(e1.y);
            afr[6] = (short)f2bf(e1.z); afr[7] = (short)f2bf(e1.w);
        }
        #pragma unroll
        for (int ct = 0; ct < 8; ++ct) {
            const short8v b = *reinterpret_cast<const short8v*>(
                WoT + (size_t)(ct * 16 + l15) * DIM + kc * 32 + lg * 8);
            acc1[ct] = __builtin_amdgcn_mfma_f32_16x16x32_bf16(afr, b, acc1[ct], 0, 0, 0);
        }
    }

    float s1[4] = {0.f, 0.f, 0.f, 0.f}, s2[4] = {0.f, 0.f, 0.f, 0.f};
    #pragma unroll
    for (int ct = 0; ct < 8; ++ct) {
        const float bov = bo[ct * 16 + l15];
        #pragma unroll
        for (int i = 0; i < 4; ++i) {
            const float v2 = (acc1[ct][i] + bov) * mk[i];
            acc1[ct][i] = v2;
            s1[i] += v2; s2[i] += v2 * v2;
        }
    }
    #pragma unroll
    for (int off = 1; off <= 8; off <<= 1) {
        #pragma unroll
        for (int i = 0; i < 4; ++i) {
            s1[i] += __shfl_xor(s1[i], off, 64);
            s2[i] += __shfl_xor(s2[i], off, 64);
        }
    }
    float mean[4], rsv[4];
    #pragma unroll
    for (int i = 0; i < 4; ++i) {
        mean[i] = s1[i] * (1.0f / OUTD);
        const float var = s2[i] * (1.0f / OUTD) - mean[i] * mean[i];
        rsv[i] = rsqrtf(var + LN_EPS);
    }
    #pragma unroll
    for (int ct = 0; ct < 8; ++ct) {
        const int col = ct * 16 + l15;
        const float sc = ln2_s[col], ofs = ln2_b[col];
        #pragma unroll
        for (int i = 0; i < 4; ++i) {
            const float h = (acc1[ct][i] - mean[i]) * rsv[i] * sc + ofs;
            lds_wr16(hls, w * 16 + r0 + i, col, f2bf(h));
        }
    }
    __syncthreads();

    short8v hfr[4];
    #pragma unroll
    for (int kc = 0; kc < 4; ++kc)
        hfr[kc] = lds_rd128(hls, arow, kc * 64 + lg * 16);

    f32x4 acc3[8];
    #pragma unroll
    for (int ct = 0; ct < 8; ++ct) acc3[ct] = (f32x4){0.f, 0.f, 0.f, 0.f};

    for (int chunk = 0; chunk < 4; ++chunk) {
        f32x4 acc2[8];
        #pragma unroll
        for (int ct = 0; ct < 8; ++ct) acc2[ct] = (f32x4){0.f, 0.f, 0.f, 0.f};
        #pragma unroll
        for (int kc = 0; kc < 4; ++kc) {
            #pragma unroll
            for (int ct = 0; ct < 8; ++ct) {
                const short8v b = *reinterpret_cast<const short8v*>(
                    W1T + (size_t)(chunk * 128 + ct * 16 + l15) * DIM + kc * 32 + lg * 8);
                acc2[ct] = __builtin_amdgcn_mfma_f32_16x16x32_bf16(hfr[kc], b, acc2[ct], 0, 0, 0);
            }
        }
        #pragma unroll
        for (int ct = 0; ct < 8; ++ct) {
            const float bv = b1[chunk * 128 + ct * 16 + l15];
            #pragma unroll
            for (int i = 0; i < 4; ++i) {
                const float tv = fmaxf(acc2[ct][i] + bv, 0.f);
                lds_wr16(tls, w * 16 + r0 + i, ct * 16 + l15, f2bf(tv));
            }
        }
        __syncthreads();
        #pragma unroll
        for (int kc = 0; kc < 4; ++kc) {
            const short8v tfr = lds_rd128(tls, arow, kc * 64 + lg * 16);
            #pragma unroll
            for (int ct = 0; ct < 8; ++ct) {
                const short8v b = *reinterpret_cast<const short8v*>(
                    W2T + (size_t)(ct * 16 + l15) * FFD + chunk * 128 + kc * 32 + lg * 8);
                acc3[ct] = __builtin_amdgcn_mfma_f32_16x16x32_bf16(tfr, b, acc3[ct], 0, 0, 0);
            }
        }
        __syncthreads();
    }

    #pragma unroll
    for (int ct = 0; ct < 8; ++ct) {
        const int col = ct * 16 + l15;
        const float b2v = b2[col];
        #pragma unroll
        for (int i = 0; i < 4; ++i) {
            const int node = nb + w * 16 + r0 + i;
            if (node < N_NODES) {
                const float f = (acc3[ct][i] + b2v) * mk[i];
                outp[(size_t)node * DIM + col] = xg[(size_t)node * DIM + col] + f;
            }
        }
    }
}

// ---------------------------------------------------------------------------
extern "C" void kernel_launch(void* const* d_in, const int* in_sizes, int n_in,
                              void* d_out, int out_size, void* d_ws, size_t ws_size,
                              hipStream_t stream)
{
    const float* node_rep = (const float*)d_in[0];
    const float* mask     = (const float*)d_in[1];
    const float* edge_feat= (const float*)d_in[2];
    const float* Wq = (const float*)d_in[3];
    const float* bq = (const float*)d_in[4];
    const float* Wk = (const float*)d_in[5];
    const float* bk = (const float*)d_in[6];
    const float* Wv = (const float*)d_in[7];
    const float* bv = (const float*)d_in[8];
    const float* Wo = (const float*)d_in[9];
    const float* bo = (const float*)d_in[10];
    const float* ln1_s = (const float*)d_in[11];
    const float* ln1_b = (const float*)d_in[12];
    const float* ln2_s = (const float*)d_in[13];
    const float* ln2_b = (const float*)d_in[14];
    const float* W1 = (const float*)d_in[15];
    const float* b1 = (const float*)d_in[16];
    const float* W2 = (const float*)d_in[17];
    const float* b2 = (const float*)d_in[18];
    const int* senders = (const int*)d_in[19];

    float* out = (float*)d_out;
    float* xg = (float*)d_ws;                           // [N,128] f32
    float* qg = xg + (size_t)N_NODES * DIM;             // [N,128] f32
    float* og = qg + (size_t)N_NODES * DIM;             // [N,128] f32
    unsigned short* Pp   = (unsigned short*)(og + (size_t)N_NODES * DIM);  // [N,256] bf16 packed
    unsigned short* WkvT = Pp + (size_t)N_NODES * 256;  // [256,64]
    unsigned short* WoT  = WkvT + 256 * 64;             // [128,128]
    unsigned short* W1T  = WoT + 128 * 128;             // [512,128]
    unsigned short* W2T  = W1T + 512 * 128;             // [128,512]

    hipLaunchKernelGGL(k0_prep, dim3(640), dim3(256), 0, stream,
                       Wk, Wv, Wo, W1, W2, WkvT, WoT, W1T, W2T);
    hipLaunchKernelGGL(k1_ln_q_p, dim3(N_NODES / 8), dim3(256), 0, stream,
                       node_rep, mask, ln1_s, ln1_b, Wq, bq, Wk, bk, Wv, bv,
                       xg, qg, Pp);
    hipLaunchKernelGGL(k2_attn, dim3(N_NODES / 4), dim3(256), 0, stream,
                       qg, edge_feat, Pp, WkvT, senders, og);
    hipLaunchKernelGGL(k3_ffn, dim3((N_NODES + 63) / 64), dim3(256), 0, stream,
                       og, xg, mask, WoT, bo, ln2_s, ln2_b, W1T, b1, W2T, b2, out);
}

// Round 7
// 279.397 us; speedup vs baseline: 1.2310x; 1.0478x over previous
//
#include <hip/hip_runtime.h>
#include <math.h>

#define N_NODES 20000
#define KNBR 32
#define DIM 128
#define EDIM 64
#define HEADS 8
#define OUTD 128
#define FFD 512
#define LN_EPS 1e-5f

typedef __attribute__((ext_vector_type(8))) short short8v;
typedef __attribute__((ext_vector_type(4))) float f32x4;

__device__ __forceinline__ unsigned short f2bf(float f) {
    unsigned u = __builtin_bit_cast(unsigned, f);
    u += 0x7fffu + ((u >> 16) & 1u);
    return (unsigned short)(u >> 16);
}

// pack 8 f32 -> 8 bf16 via the proven scalar path (compiler schedules well)
__device__ __forceinline__ short8v pack8(const float4 a, const float4 b) {
    short8v r;
    r[0] = (short)f2bf(a.x); r[1] = (short)f2bf(a.y);
    r[2] = (short)f2bf(a.z); r[3] = (short)f2bf(a.w);
    r[4] = (short)f2bf(b.x); r[5] = (short)f2bf(b.y);
    r[6] = (short)f2bf(b.z); r[7] = (short)f2bf(b.w);
    return r;
}

// DPP 16-lane all-lanes sum (VALU only, no DS)
template <int CTRL>
__device__ __forceinline__ float dpp_addf(float x) {
    const int s = __builtin_bit_cast(int, x);
    const int p = __builtin_amdgcn_update_dpp(s, s, CTRL, 0xF, 0xF, true);
    return x + __builtin_bit_cast(float, p);
}
__device__ __forceinline__ float red16(float x) {
    x = dpp_addf<0xB1>(x);
    x = dpp_addf<0x4E>(x);
    x = dpp_addf<0x141>(x);
    x = dpp_addf<0x140>(x);
    return x;
}

// ---------------------------------------------------------------------------
// K0: weight prep.
//   WkvTf: FRAGMENT-MAJOR [32 frags][64 lanes][8 bf16] — frag = cc*2+s;
//          lane (l15,lg) holds [Wk|Wv]-col (16cc+l15), edge-rows s*32+lg*8..+7
//   WoT [c][d] = Wo[d][c] ; W1T [f][d] = W1[d][f] ; W2T [c][f] = W2[f][c]
// ---------------------------------------------------------------------------
__global__ __launch_bounds__(256) void k0_prep(
    const float* __restrict__ Wk, const float* __restrict__ Wv,
    const float* __restrict__ Wo, const float* __restrict__ W1,
    const float* __restrict__ W2,
    unsigned short* __restrict__ WkvTf, unsigned short* __restrict__ WoT,
    unsigned short* __restrict__ W1T, unsigned short* __restrict__ W2T)
{
    const int idx = blockIdx.x * 256 + threadIdx.x;   // 163840 total
    if (idx < 16384) {
        const int frag = idx >> 9;          // cc*2 + s
        const int e    = idx & 511;
        const int lane = e >> 3, j = e & 7;
        const int cc = frag >> 1, s = frag & 1;
        const int c  = cc * 16 + (lane & 15);
        const int m  = s * 32 + (lane >> 4) * 8 + j;
        WkvTf[idx] = f2bf((c < 128) ? Wk[(size_t)(128 + m) * 128 + c]
                                    : Wv[(size_t)(128 + m) * 128 + (c - 128)]);
    } else if (idx < 32768) {
        const int j = idx - 16384, c = j >> 7, d = j & 127;
        WoT[j] = f2bf(Wo[(size_t)d * 128 + c]);
    } else if (idx < 98304) {
        const int j = idx - 32768, f = j >> 7, d = j & 127;
        W1T[j] = f2bf(W1[(size_t)d * 512 + f]);
    } else {
        const int j = idx - 98304, c = j >> 9, f = j & 511;
        W2T[j] = f2bf(W2[(size_t)f * 128 + c]);
    }
}

// ---------------------------------------------------------------------------
// K1: x = LN(node_rep)*mask -> xout ; q = x@Wq+bq -> qout ;
//     P = x@[Wk_x|Wv_x] + [bk|bv] -> Pp (bf16, ROW-MAJOR [n][256])
// ---------------------------------------------------------------------------
__global__ __launch_bounds__(256) void k1_ln_q_p(
    const float* __restrict__ node_rep, const float* __restrict__ mask,
    const float* __restrict__ ln1_s, const float* __restrict__ ln1_b,
    const float* __restrict__ Wq, const float* __restrict__ bq,
    const float* __restrict__ Wk, const float* __restrict__ bk,
    const float* __restrict__ Wv, const float* __restrict__ bv,
    float* __restrict__ xout, float* __restrict__ qout,
    unsigned short* __restrict__ Pp)
{
    __shared__ float xs[8][DIM];
    const int t = threadIdx.x;
    const int nb = blockIdx.x * 8;
    const int g = t >> 5;
    const int lane = t & 31;
    const int node = nb + g;

    float4 v = reinterpret_cast<const float4*>(node_rep + (size_t)node * DIM)[lane];
    float s1 = v.x + v.y + v.z + v.w;
    float s2 = v.x * v.x + v.y * v.y + v.z * v.z + v.w * v.w;
    #pragma unroll
    for (int off = 16; off; off >>= 1) {
        s1 += __shfl_xor(s1, off, 32);
        s2 += __shfl_xor(s2, off, 32);
    }
    const float mean = s1 * (1.0f / DIM);
    const float var  = s2 * (1.0f / DIM) - mean * mean;
    const float rs   = rsqrtf(var + LN_EPS);
    const float mk   = mask[node];

    float4 sc = reinterpret_cast<const float4*>(ln1_s)[lane];
    float4 of = reinterpret_cast<const float4*>(ln1_b)[lane];
    float4 xo;
    xo.x = ((v.x - mean) * rs * sc.x + of.x) * mk;
    xo.y = ((v.y - mean) * rs * sc.y + of.y) * mk;
    xo.z = ((v.z - mean) * rs * sc.z + of.z) * mk;
    xo.w = ((v.w - mean) * rs * sc.w + of.w) * mk;
    reinterpret_cast<float4*>(xout + (size_t)node * DIM)[lane] = xo;
    const int c0 = lane * 4;
    xs[g][c0 + 0] = xo.x; xs[g][c0 + 1] = xo.y;
    xs[g][c0 + 2] = xo.z; xs[g][c0 + 3] = xo.w;
    __syncthreads();

    const int col = t & 127;
    const int n0  = t >> 7;
    const int c = t;
    const float* wq = Wq + col;
    const float* wp = (c < 128) ? (Wk + c) : (Wv + (c - 128));

    float accq[4] = {0.f, 0.f, 0.f, 0.f};
    float accp[8] = {0.f, 0.f, 0.f, 0.f, 0.f, 0.f, 0.f, 0.f};
    for (int d = 0; d < DIM; ++d) {
        const float wqd = wq[(size_t)d * 128];
        const float wpd = wp[(size_t)d * 128];
        #pragma unroll
        for (int i = 0; i < 4; ++i) accq[i] += xs[n0 + 2 * i][d] * wqd;
        #pragma unroll
        for (int i = 0; i < 8; ++i) accp[i] += xs[i][d] * wpd;
    }
    const float bqv = bq[col];
    #pragma unroll
    for (int i = 0; i < 4; ++i)
        qout[(size_t)(nb + n0 + 2 * i) * DIM + col] = accq[i] + bqv;

    const float bpv = (c < 128) ? bk[c] : bv[c - 128];
    #pragma unroll
    for (int i = 0; i < 8; ++i)
        Pp[(size_t)(nb + i) * 256 + c] = f2bf(accp[i] + bpv);
}

// ---------------------------------------------------------------------------
// K2: per-node attention via MFMA. 1 wave = 1 node, 4 nodes/block, no LDS.
//   E-GEMM: B-fragments from fragment-major WkvTf (coalesced lane*16B loads).
//   P[snd] added via identity-MFMA (A = gathered P rows, B = register I).
//   Epilogue: DPP reductions.
// ---------------------------------------------------------------------------
__global__ __launch_bounds__(256, 2) void k2_attn(
    const float* __restrict__ qg, const float* __restrict__ edge_feat,
    const unsigned short* __restrict__ Pp,
    const unsigned short* __restrict__ WkvTf,
    const int* __restrict__ senders,
    float* __restrict__ og)
{
    const int t = threadIdx.x;
    const int w = t >> 6, l = t & 63;
    const int n = blockIdx.x * 4 + w;
    const int l15 = l & 15, lg = l >> 4;

    // per-lane neighbor rows for the two 16-row tiles
    const int s0 = senders[n * KNBR + l15];
    const int s1 = senders[n * KNBR + 16 + l15];

    // per-head q values for this lane's column: q[h*16 + l15]
    float qreg[8];
    #pragma unroll
    for (int h = 0; h < 8; ++h)
        qreg[h] = qg[(size_t)n * DIM + h * 16 + l15];

    f32x4 acc[2][16];
    #pragma unroll
    for (int r = 0; r < 2; ++r)
        #pragma unroll
        for (int cc = 0; cc < 16; ++cc)
            acc[r][cc] = (f32x4){0.f, 0.f, 0.f, 0.f};

    // A fragments: edge rows, f32 -> bf16 (proven scalar path)
    short8v afr[2][2];
    #pragma unroll
    for (int r = 0; r < 2; ++r) {
        #pragma unroll
        for (int s = 0; s < 2; ++s) {
            const float* ep = edge_feat
                + ((size_t)n * KNBR + 16 * r + l15) * EDIM + s * 32 + lg * 8;
            const float4 e0 = *reinterpret_cast<const float4*>(ep);
            const float4 e1 = *reinterpret_cast<const float4*>(ep + 4);
            afr[r][s] = pack8(e0, e1);
        }
    }

    // E-MFMA: acc[r][cc] += A_edge[r][s] * Wkv[cc][s]   (B coalesced)
    #pragma unroll
    for (int cc = 0; cc < 16; ++cc) {
        #pragma unroll
        for (int s = 0; s < 2; ++s) {
            const short8v b = *reinterpret_cast<const short8v*>(
                WkvTf + (((size_t)(cc * 2 + s)) << 9) + l * 8);
            acc[0][cc] = __builtin_amdgcn_mfma_f32_16x16x32_bf16(
                afr[0][s], b, acc[0][cc], 0, 0, 0);
            acc[1][cc] = __builtin_amdgcn_mfma_f32_16x16x32_bf16(
                afr[1][s], b, acc[1][cc], 0, 0, 0);
        }
    }

    // identity B-fragments: ib1[m][c]=d(m==c), ib2[m][c]=d(m==c+16), m=lg*8+j
    short8v ib1, ib2;
    #pragma unroll
    for (int j = 0; j < 8; ++j) {
        const int m = lg * 8 + j;
        ib1[j] = (m == l15)      ? (short)0x3F80 : (short)0;
        ib2[j] = (m == l15 + 16) ? (short)0x3F80 : (short)0;
    }

    // P-add via identity MFMA: acc[r][2c2+b][lane] += P[snd_row][32c2+16b+l15]
    #pragma unroll
    for (int c2 = 0; c2 < 8; ++c2) {
        const short8v pa0 = *reinterpret_cast<const short8v*>(
            Pp + (size_t)s0 * 256 + c2 * 32 + lg * 8);
        const short8v pa1 = *reinterpret_cast<const short8v*>(
            Pp + (size_t)s1 * 256 + c2 * 32 + lg * 8);
        acc[0][2 * c2]     = __builtin_amdgcn_mfma_f32_16x16x32_bf16(
            pa0, ib1, acc[0][2 * c2], 0, 0, 0);
        acc[0][2 * c2 + 1] = __builtin_amdgcn_mfma_f32_16x16x32_bf16(
            pa0, ib2, acc[0][2 * c2 + 1], 0, 0, 0);
        acc[1][2 * c2]     = __builtin_amdgcn_mfma_f32_16x16x32_bf16(
            pa1, ib1, acc[1][2 * c2], 0, 0, 0);
        acc[1][2 * c2 + 1] = __builtin_amdgcn_mfma_f32_16x16x32_bf16(
            pa1, ib2, acc[1][2 * c2 + 1], 0, 0, 0);
    }

    // epilogue per head: logits -> softmax -> PV. DPP reductions (no DS).
    #pragma unroll
    for (int h = 0; h < 8; ++h) {
        const float qv = qreg[h];
        float tm[8];
        #pragma unroll
        for (int r = 0; r < 2; ++r)
            #pragma unroll
            for (int i = 0; i < 4; ++i)
                tm[r * 4 + i] = acc[r][h][i] * qv;
        // sum over l15 (feature dim of head) -> all lanes, VALU-only
        #pragma unroll
        for (int k = 0; k < 8; ++k) tm[k] = red16(tm[k]);
        // max over 32 neighbors: 8 local + cross-lg
        float m = tm[0];
        #pragma unroll
        for (int k = 1; k < 8; ++k) m = fmaxf(m, tm[k]);
        m = fmaxf(m, __shfl_xor(m, 16, 64));
        m = fmaxf(m, __shfl_xor(m, 32, 64));
        float s = 0.f, at[8];
        #pragma unroll
        for (int k = 0; k < 8; ++k) {
            at[k] = __expf((tm[k] - m) * 0.25f);
            s += at[k];
        }
        s += __shfl_xor(s, 16, 64);
        s += __shfl_xor(s, 32, 64);
        const float inv = 1.0f / s;
        float ov = 0.f;
        #pragma unroll
        for (int r = 0; r < 2; ++r)
            #pragma unroll
            for (int i = 0; i < 4; ++i)
                ov += at[r * 4 + i] * acc[r][8 + h][i];
        ov += __shfl_xor(ov, 16, 64);
        ov += __shfl_xor(ov, 32, 64);
        ov *= inv;
        if (lg == 0)
            og[(size_t)n * DIM + h * 16 + l15] = ov;
    }
}

// ---------------------------------------------------------------------------
// K3 (MFMA): res=o@Wo+bo; *mask; LN2 (in C-frag regs); h->LDS(bf16,swizzled);
//   chunked FF: t=relu(h@W1+b1) chunk->LDS; acc3 += t@W2 ; +b2,*mask,+x -> out
// ---------------------------------------------------------------------------
__device__ __forceinline__ void lds_wr16(unsigned short* base, int row, int col,
                                         unsigned short v) {
    const int byte = row * 256 + (((col * 2) ^ ((row & 7) << 4)));
    *reinterpret_cast<unsigned short*>(reinterpret_cast<char*>(base) + byte) = v;
}
__device__ __forceinline__ short8v lds_rd128(const unsigned short* base, int row,
                                             int colbyte) {
    const int byte = row * 256 + ((colbyte) ^ ((row & 7) << 4));
    return *reinterpret_cast<const short8v*>(
        reinterpret_cast<const char*>(base) + byte);
}

__global__ __launch_bounds__(256) void k3_ffn(
    const float* __restrict__ og, const float* __restrict__ xg,
    const float* __restrict__ mask,
    const unsigned short* __restrict__ WoT, const float* __restrict__ bo,
    const float* __restrict__ ln2_s, const float* __restrict__ ln2_b,
    const unsigned short* __restrict__ W1T, const float* __restrict__ b1,
    const unsigned short* __restrict__ W2T, const float* __restrict__ b2,
    float* __restrict__ outp)
{
    __shared__ unsigned short hls[64 * 128];
    __shared__ unsigned short tls[64 * 128];

    const int t = threadIdx.x;
    const int w = t >> 6, l = t & 63;
    const int l15 = l & 15, lg = l >> 4;
    const int nb = blockIdx.x * 64;
    const int arow = w * 16 + l15;
    const int anode = nb + arow;
    const int r0 = lg * 4;

    float mk[4];
    #pragma unroll
    for (int i = 0; i < 4; ++i) {
        const int node = nb + w * 16 + r0 + i;
        mk[i] = (node < N_NODES) ? mask[node] : 0.f;
    }

    f32x4 acc1[8];
    #pragma unroll
    for (int ct = 0; ct < 8; ++ct) acc1[ct] = (f32x4){0.f, 0.f, 0.f, 0.f};
    #pragma unroll
    for (int kc = 0; kc < 4; ++kc) {
        short8v afr = {0, 0, 0, 0, 0, 0, 0, 0};
        if (anode < N_NODES) {
            const float* op = og + (size_t)anode * DIM + kc * 32 + lg * 8;
            const float4 e0 = *reinterpret_cast<const float4*>(op);
            const float4 e1 = *reinterpret_cast<const float4*>(op + 4);
            afr = pack8(e0, e1);
        }
        #pragma unroll
        for (int ct = 0; ct < 8; ++ct) {
            const short8v b = *reinterpret_cast<const short8v*>(
                WoT + (size_t)(ct * 16 + l15) * DIM + kc * 32 + lg * 8);
            acc1[ct] = __builtin_amdgcn_mfma_f32_16x16x32_bf16(afr, b, acc1[ct], 0, 0, 0);
        }
    }

    float s1[4] = {0.f, 0.f, 0.f, 0.f}, s2[4] = {0.f, 0.f, 0.f, 0.f};
    #pragma unroll
    for (int ct = 0; ct < 8; ++ct) {
        const float bov = bo[ct * 16 + l15];
        #pragma unroll
        for (int i = 0; i < 4; ++i) {
            const float v2 = (acc1[ct][i] + bov) * mk[i];
            acc1[ct][i] = v2;
            s1[i] += v2; s2[i] += v2 * v2;
        }
    }
    #pragma unroll
    for (int off = 1; off <= 8; off <<= 1) {
        #pragma unroll
        for (int i = 0; i < 4; ++i) {
            s1[i] += __shfl_xor(s1[i], off, 64);
            s2[i] += __shfl_xor(s2[i], off, 64);
        }
    }
    float mean[4], rsv[4];
    #pragma unroll
    for (int i = 0; i < 4; ++i) {
        mean[i] = s1[i] * (1.0f / OUTD);
        const float var = s2[i] * (1.0f / OUTD) - mean[i] * mean[i];
        rsv[i] = rsqrtf(var + LN_EPS);
    }
    #pragma unroll
    for (int ct = 0; ct < 8; ++ct) {
        const int col = ct * 16 + l15;
        const float sc = ln2_s[col], ofs = ln2_b[col];
        #pragma unroll
        for (int i = 0; i < 4; ++i) {
            const float h = (acc1[ct][i] - mean[i]) * rsv[i] * sc + ofs;
            lds_wr16(hls, w * 16 + r0 + i, col, f2bf(h));
        }
    }
    __syncthreads();

    short8v hfr[4];
    #pragma unroll
    for (int kc = 0; kc < 4; ++kc)
        hfr[kc] = lds_rd128(hls, arow, kc * 64 + lg * 16);

    f32x4 acc3[8];
    #pragma unroll
    for (int ct = 0; ct < 8; ++ct) acc3[ct] = (f32x4){0.f, 0.f, 0.f, 0.f};

    for (int chunk = 0; chunk < 4; ++chunk) {
        f32x4 acc2[8];
        #pragma unroll
        for (int ct = 0; ct < 8; ++ct) acc2[ct] = (f32x4){0.f, 0.f, 0.f, 0.f};
        #pragma unroll
        for (int kc = 0; kc < 4; ++kc) {
            #pragma unroll
            for (int ct = 0; ct < 8; ++ct) {
                const short8v b = *reinterpret_cast<const short8v*>(
                    W1T + (size_t)(chunk * 128 + ct * 16 + l15) * DIM + kc * 32 + lg * 8);
                acc2[ct] = __builtin_amdgcn_mfma_f32_16x16x32_bf16(hfr[kc], b, acc2[ct], 0, 0, 0);
            }
        }
        #pragma unroll
        for (int ct = 0; ct < 8; ++ct) {
            const float bv = b1[chunk * 128 + ct * 16 + l15];
            #pragma unroll
            for (int i = 0; i < 4; ++i) {
                const float tv = fmaxf(acc2[ct][i] + bv, 0.f);
                lds_wr16(tls, w * 16 + r0 + i, ct * 16 + l15, f2bf(tv));
            }
        }
        __syncthreads();
        #pragma unroll
        for (int kc = 0; kc < 4; ++kc) {
            const short8v tfr = lds_rd128(tls, arow, kc * 64 + lg * 16);
            #pragma unroll
            for (int ct = 0; ct < 8; ++ct) {
                const short8v b = *reinterpret_cast<const short8v*>(
                    W2T + (size_t)(ct * 16 + l15) * FFD + chunk * 128 + kc * 32 + lg * 8);
                acc3[ct] = __builtin_amdgcn_mfma_f32_16x16x32_bf16(tfr, b, acc3[ct], 0, 0, 0);
            }
        }
        __syncthreads();
    }

    #pragma unroll
    for (int ct = 0; ct < 8; ++ct) {
        const int col = ct * 16 + l15;
        const float b2v = b2[col];
        #pragma unroll
        for (int i = 0; i < 4; ++i) {
            const int node = nb + w * 16 + r0 + i;
            if (node < N_NODES) {
                const float f = (acc3[ct][i] + b2v) * mk[i];
                outp[(size_t)node * DIM + col] = xg[(size_t)node * DIM + col] + f;
            }
        }
    }
}

// ---------------------------------------------------------------------------
extern "C" void kernel_launch(void* const* d_in, const int* in_sizes, int n_in,
                              void* d_out, int out_size, void* d_ws, size_t ws_size,
                              hipStream_t stream)
{
    const float* node_rep = (const float*)d_in[0];
    const float* mask     = (const float*)d_in[1];
    const float* edge_feat= (const float*)d_in[2];
    const float* Wq = (const float*)d_in[3];
    const float* bq = (const float*)d_in[4];
    const float* Wk = (const float*)d_in[5];
    const float* bk = (const float*)d_in[6];
    const float* Wv = (const float*)d_in[7];
    const float* bv = (const float*)d_in[8];
    const float* Wo = (const float*)d_in[9];
    const float* bo = (const float*)d_in[10];
    const float* ln1_s = (const float*)d_in[11];
    const float* ln1_b = (const float*)d_in[12];
    const float* ln2_s = (const float*)d_in[13];
    const float* ln2_b = (const float*)d_in[14];
    const float* W1 = (const float*)d_in[15];
    const float* b1 = (const float*)d_in[16];
    const float* W2 = (const float*)d_in[17];
    const float* b2 = (const float*)d_in[18];
    const int* senders = (const int*)d_in[19];

    float* out = (float*)d_out;
    float* xg = (float*)d_ws;                           // [N,128] f32
    float* qg = xg + (size_t)N_NODES * DIM;             // [N,128] f32
    float* og = qg + (size_t)N_NODES * DIM;             // [N,128] f32
    unsigned short* Pp    = (unsigned short*)(og + (size_t)N_NODES * DIM);  // [N,256] bf16 row-major
    unsigned short* WkvTf = Pp + (size_t)N_NODES * 256;  // [32 frag][512]
    unsigned short* WoT   = WkvTf + 256 * 64;            // [128,128]
    unsigned short* W1T   = WoT + 128 * 128;             // [512,128]
    unsigned short* W2T   = W1T + 512 * 128;             // [128,512]

    hipLaunchKernelGGL(k0_prep, dim3(640), dim3(256), 0, stream,
                       Wk, Wv, Wo, W1, W2, WkvTf, WoT, W1T, W2T);
    hipLaunchKernelGGL(k1_ln_q_p, dim3(N_NODES / 8), dim3(256), 0, stream,
                       node_rep, mask, ln1_s, ln1_b, Wq, bq, Wk, bk, Wv, bv,
                       xg, qg, Pp);
    hipLaunchKernelGGL(k2_attn, dim3(N_NODES / 4), dim3(256), 0, stream,
                       qg, edge_feat, Pp, WkvTf, senders, og);
    hipLaunchKernelGGL(k3_ffn, dim3((N_NODES + 63) / 64), dim3(256), 0, stream,
                       og, xg, mask, WoT, bo, ln2_s, ln2_b, W1T, b1, W2T, b2, out);
}